// Round 16
// baseline (123.902 us; speedup 1.0000x reference)
//
#include <hip/hip_runtime.h>
#include <hip/hip_bf16.h>

#define NS 512
#define NB 2048
#define NT 32
#define NF 64
#define NH 128
#define NFX 80   // B cols: 64 bgX + y(64) + ones(65) + zeros(66..79)
#define PSTR 81  // part[] stride

// output float offsets: [leaf_xs (S,T,F)][leaf_y (S,T)][alphas (S,B,T)]
#define OY  ((size_t)NS * NT * NF)
#define OA  (OY + (size_t)NS * NT)

#define ENC_B  1280
#define TR_B   32

typedef __attribute__((ext_vector_type(8))) short bf16x8;
typedef __attribute__((ext_vector_type(4))) float f32x4;

__device__ __forceinline__ unsigned short f2bfu(float x) {
    __hip_bfloat16 h = __float2bfloat16(x);
    return __builtin_bit_cast(unsigned short, h);
}

// bit j of result = (byte j of v != 0), j in [0,16)
__device__ __forceinline__ unsigned int pack16_bytes(uint4 v) {
    unsigned int r = 0;
    unsigned int xs[4] = {v.x, v.y, v.z, v.w};
    #pragma unroll
    for (int i = 0; i < 4; ++i) {
        unsigned int x = xs[i];
        unsigned int t = (x | ((x & 0x7F7F7F7Fu) + 0x7F7F7F7Fu)) & 0x80808080u;
        t >>= 7;
        unsigned int n = (t | (t >> 7) | (t >> 14) | (t >> 21)) & 0xFu;
        r |= n << (i * 4);
    }
    return r;
}

// per-wave mask layout detect over the 4KB header (uniform w.h.p.: int32 0/1 words
// have zero bytes at offsets %4!=0; random byte-bools don't — 768 random bits/wave)
__device__ __forceinline__ int detect_isbyte(const void* mask, int tid) {
    uint4 v = ((const uint4*)mask)[tid & 255];
    return (__ballot(((v.x | v.y | v.z | v.w) & 0xFFFFFF00u) != 0u) != 0ull);
}

// ---------- prep2: encode (blocks 0..1279, 2 rows each) + frag-transpose (1280..1311) ----------
__global__ __launch_bounds__(256) void prep2_k(
        const float* __restrict__ X, const float* __restrict__ bgX,
        const float* __restrict__ bgy,
        const float* __restrict__ W1, const float* __restrict__ b1,
        const float* __restrict__ W2, const float* __restrict__ b2,
        float* __restrict__ enc, unsigned short* __restrict__ bgXT2) {
    __shared__ float cbuf[64 * 65];
    const int blk = blockIdx.x;
    const int tid = threadIdx.x;

    if (blk < ENC_B) {                   // ---- encode branch: 2 rows per block ----
        const int r0 = blk * 2;
        float* xr = cbuf;                // [2][64]
        float* hr = cbuf + 128;          // [2][128]
        if (tid < 128) {
            int r = tid >> 6, c = tid & 63;
            int row = r0 + r;
            const float* src = (row < NS) ? (X + (size_t)row * NF)
                                          : (bgX + (size_t)(row - NS) * NF);
            xr[r * 64 + c] = src[c];
        }
        __syncthreads();
        const int j = tid & 127, h = tid >> 7;
        const float* xh = xr + h * 64;
        float a1 = b1[j];
        #pragma unroll 4
        for (int f = 0; f < NF; ++f)
            a1 = fmaf(xh[f], W1[f * NH + j], a1);
        hr[h * 128 + j] = tanhf(a1);
        __syncthreads();
        const float* hh = hr + h * 128;
        float a2 = b2[j];
        #pragma unroll 4
        for (int k = 0; k < NH; ++k)
            a2 = fmaf(hh[k], W2[k * NH + j], a2);
        enc[(size_t)(r0 + h) * NH + j] = a2;
        return;
    }

    {   // ---- frag-transpose branch: 64 b's per block -> MFMA-fragment-ordered B ----
        const int bb0 = blk - ENC_B;     // 0..31
        const int b0 = bb0 * 64;
        float (*t_lds)[65] = (float(*)[65])cbuf;
        #pragma unroll
        for (int it = 0; it < 4; ++it) {
            int idx = (it * 256 + tid) * 4;
            int r = idx >> 6, c = idx & 63;
            *(float4*)(&t_lds[r][c]) = *(const float4*)(bgX + (size_t)(b0 + r) * NF + c);
        }
        __syncthreads();
        uint4* fb = (uint4*)bgXT2;
        const int c2 = tid >> 7;
        const int cg = bb0 * 2 + c2;
        for (int idx = tid & 127; idx < 320; idx += 128) {
            const int n = idx >> 6, l = idx & 63;
            const int lo = l & 15, hi = l >> 4;
            union { unsigned short u[8]; uint4 q; } pk;
            if (n < 4) {
                #pragma unroll
                for (int jj = 0; jj < 8; ++jj)
                    pk.u[jj] = f2bfu(t_lds[c2 * 32 + hi * 8 + jj][n * 16 + lo]);
            } else {
                #pragma unroll
                for (int jj = 0; jj < 8; ++jj) {
                    if (lo == 0)      pk.u[jj] = f2bfu(bgy[b0 + c2 * 32 + hi * 8 + jj]);
                    else if (lo == 1) pk.u[jj] = 0x3F80;      // bf16 1.0
                    else              pk.u[jj] = 0;
                }
            }
            fb[((size_t)cg * 5 + n) * 64 + l] = pk.q;
        }
    }
}

// ---------- dots = X_enc @ bg_enc^T; contiguous stores, k-major Bt ----------
__global__ __launch_bounds__(256) void dots_k(const float* __restrict__ Xe,
        const float* __restrict__ Be, float* __restrict__ dots) {
    __shared__ float At[64 * 68];
    __shared__ float Bt[64 * 68];
    const int s0 = blockIdx.y * 64, b0 = blockIdx.x * 64;
    const int tid = threadIdx.x;
    const int ts = tid >> 4, tb = tid & 15;
    float acc[4][4] = {};
    for (int kt = 0; kt < 2; ++kt) {
        __syncthreads();
        #pragma unroll
        for (int it = 0; it < 4; ++it) {
            int idx = tid * 4 + it * 1024;
            int r = idx >> 6, k = idx & 63;
            *(float4*)(&At[r * 68 + k]) = *(const float4*)(Xe + (size_t)(s0 + r) * NH + kt * 64 + k);
            float4 bvv = *(const float4*)(Be + (size_t)(b0 + r) * NH + kt * 64 + k);
            Bt[(k + 0) * 68 + r] = bvv.x;
            Bt[(k + 1) * 68 + r] = bvv.y;
            Bt[(k + 2) * 68 + r] = bvv.z;
            Bt[(k + 3) * 68 + r] = bvv.w;
        }
        __syncthreads();
        #pragma unroll 4
        for (int k = 0; k < 64; ++k) {
            float4 bq = *(const float4*)(&Bt[k * 68 + tb * 4]);
            float a[4];
            #pragma unroll
            for (int i = 0; i < 4; ++i) a[i] = At[(ts + 16 * i) * 68 + k];
            #pragma unroll
            for (int i = 0; i < 4; ++i) {
                acc[i][0] = fmaf(a[i], bq.x, acc[i][0]);
                acc[i][1] = fmaf(a[i], bq.y, acc[i][1]);
                acc[i][2] = fmaf(a[i], bq.z, acc[i][2]);
                acc[i][3] = fmaf(a[i], bq.w, acc[i][3]);
            }
        }
    }
    #pragma unroll
    for (int i = 0; i < 4; ++i) {
        float4 v = make_float4(acc[i][0], acc[i][1], acc[i][2], acc[i][3]);
        *(float4*)(&dots[(size_t)(s0 + ts + 16 * i) * NB + b0 + tb * 4]) = v;
    }
}

// ---------- fusedA v2: wave-private mask pack + softmax + MFMA einsum ----------
// LDS 23KB (occupancy ~2x R15). mrow/e_bf slices are wave-local: NO barrier
// between pack/exp and einsum. Overwrites dots row with e; writes rden_g.
__global__ __launch_bounds__(256) void fusedA_k(const void* __restrict__ mask,
        float* __restrict__ dots, const unsigned short* __restrict__ bgXT2,
        float* __restrict__ rden_g, float* __restrict__ out) {
    __shared__ __align__(16) unsigned int mrow[NB];      // 8KB (wave-private slices)
    __shared__ __align__(16) unsigned short e_bf[NB];    // 4KB (wave-private slices)
    __shared__ float part[NT * PSTR];                    // 10.4KB single-slot reduce
    __shared__ float wmax[4];
    __shared__ float rden_l[NT];
    __shared__ float ytmp[NT];

    const int s = blockIdx.x;
    const int tid = threadIdx.x;
    const int lane = tid & 63, w = tid >> 6;
    const int lo = lane & 15, hi = lane >> 4;

    // ---- phase 0: dots loads + wave-private mask pack (batched 8-deep MLP) ----
    float* drow = dots + (size_t)s * NB;
    float4 d0 = *(const float4*)(drow + tid * 8);
    float4 d1 = *(const float4*)(drow + tid * 8 + 4);
    const int isbyte = detect_isbyte(mask, tid);
    if (isbyte) {                        // wave's 16KB of row s, 2 batches of 8x1KB
        const char* base = (const char*)mask + (size_t)s * 65536 + w * 16384;
        #pragma unroll
        for (int g = 0; g < 2; ++g) {
            uint4 q[8];
            #pragma unroll
            for (int k = 0; k < 8; ++k)
                q[k] = *(const uint4*)(base + (g * 8 + k) * 1024 + lane * 16);
            #pragma unroll
            for (int k = 0; k < 8; ++k) {
                unsigned int p = pack16_bytes(q[k]);
                unsigned int p1 = (unsigned int)__shfl_down((int)p, 1, 64);
                if ((lane & 1) == 0)
                    mrow[w * 512 + (g * 8 + k) * 32 + (lane >> 1)] = p | (p1 << 16);
            }
        }
    } else {                             // int32 fallback: wave's 64KB
        const char* base = (const char*)mask + (size_t)s * 262144 + w * 65536;
        for (int k = 0; k < 64; ++k) {
            uint4 v = *(const uint4*)(base + k * 1024 + lane * 16);
            unsigned int r = (v.x ? 1u : 0u) | (v.y ? 2u : 0u) |
                             (v.z ? 4u : 0u) | (v.w ? 8u : 0u);
            r |= ((unsigned int)__shfl_down((int)r, 1, 64)) << 4;
            r |= ((unsigned int)__shfl_down((int)r, 2, 64)) << 8;
            r |= ((unsigned int)__shfl_down((int)r, 4, 64)) << 16;
            if ((lane & 7) == 0)
                mrow[w * 512 + k * 8 + (lane >> 3)] = r;
        }
    }

    // ---- phase 1: row max (cross-wave -> one barrier), exp; e -> global + LDS bf16 ----
    float pmax = fmaxf(fmaxf(fmaxf(d0.x, d0.y), fmaxf(d0.z, d0.w)),
                       fmaxf(fmaxf(d1.x, d1.y), fmaxf(d1.z, d1.w)));
    #pragma unroll
    for (int off = 32; off >= 1; off >>= 1)
        pmax = fmaxf(pmax, __shfl_xor(pmax, off, 64));
    if (lane == 0) wmax[w] = pmax;
    __syncthreads();
    const float Ms = fmaxf(fmaxf(wmax[0], wmax[1]), fmaxf(wmax[2], wmax[3]));
    float ev[8] = {d0.x, d0.y, d0.z, d0.w, d1.x, d1.y, d1.z, d1.w};
    union { unsigned short u[8]; uint4 q; } epk;
    #pragma unroll
    for (int q = 0; q < 8; ++q) { ev[q] = __expf(ev[q] - Ms); epk.u[q] = f2bfu(ev[q]); }
    *(float4*)(drow + tid * 8)     = make_float4(ev[0], ev[1], ev[2], ev[3]);
    *(float4*)(drow + tid * 8 + 4) = make_float4(ev[4], ev[5], ev[6], ev[7]);
    *(uint4*)(&e_bf[tid * 8]) = epk.q;   // tid*8 spans exactly wave w's slice
    // NO barrier: einsum below reads only this wave's mrow/e_bf slices.

    // ---- phase 2: MFMA over K (wave w owns b in [w*512, w*512+512)) ----
    f32x4 acc[2][5] = {};
    const uint4* fb = (const uint4*)bgXT2;
    #pragma unroll 2
    for (int ks = 0; ks < 16; ++ks) {
        const int bb = w * 512 + ks * 32 + hi * 8;
        uint4 ew4 = *(const uint4*)(&e_bf[bb]);
        uint4 m0 = *(const uint4*)(&mrow[bb]);
        uint4 m1 = *(const uint4*)(&mrow[bb + 4]);
        unsigned int ew[4] = {ew4.x, ew4.y, ew4.z, ew4.w};
        unsigned int mv[8] = {m0.x, m0.y, m0.z, m0.w, m1.x, m1.y, m1.z, m1.w};
        unsigned int A0[4], A1[4];
        #pragma unroll
        for (int p = 0; p < 4; ++p) {
            unsigned int mlo = mv[2 * p]     >> lo;
            unsigned int mhi = mv[2 * p + 1] >> lo;
            unsigned int k0 = ((mlo & 1u)       ? 0x0000FFFFu : 0u) |
                              ((mhi & 1u)       ? 0xFFFF0000u : 0u);
            unsigned int k1 = ((mlo & 0x10000u) ? 0x0000FFFFu : 0u) |
                              ((mhi & 0x10000u) ? 0xFFFF0000u : 0u);
            A0[p] = ew[p] & k0;
            A1[p] = ew[p] & k1;
        }
        bf16x8 a0 = __builtin_bit_cast(bf16x8, make_uint4(A0[0], A0[1], A0[2], A0[3]));
        bf16x8 a1 = __builtin_bit_cast(bf16x8, make_uint4(A1[0], A1[1], A1[2], A1[3]));
        const uint4* fr = fb + ((size_t)(w * 16 + ks) * 5) * 64 + lane;
        #pragma unroll
        for (int n = 0; n < 5; ++n) {
            uint4 bv = fr[n * 64];
            bf16x8 bfr = __builtin_bit_cast(bf16x8, bv);
            acc[0][n] = __builtin_amdgcn_mfma_f32_16x16x32_bf16(a0, bfr, acc[0][n], 0, 0, 0);
            acc[1][n] = __builtin_amdgcn_mfma_f32_16x16x32_bf16(a1, bfr, acc[1][n], 0, 0, 0);
        }
    }

    // ---- phase 3: sequential cross-wave reduce (single 10.4KB slot, R9-proven) ----
    for (int src = 1; src < 4; ++src) {
        __syncthreads();
        if (w == src) {
            #pragma unroll
            for (int m = 0; m < 2; ++m)
                #pragma unroll
                for (int n = 0; n < 5; ++n)
                    #pragma unroll
                    for (int r = 0; r < 4; ++r) {
                        int t = m * 16 + hi * 4 + r, f = n * 16 + lo;
                        part[t * PSTR + f] = acc[m][n][r];
                    }
        }
        __syncthreads();
        if (w == 0) {
            #pragma unroll
            for (int m = 0; m < 2; ++m)
                #pragma unroll
                for (int n = 0; n < 5; ++n)
                    #pragma unroll
                    for (int r = 0; r < 4; ++r) {
                        int t = m * 16 + hi * 4 + r, f = n * 16 + lo;
                        acc[m][n][r] += part[t * PSTR + f];
                    }
        }
    }
    if (w == 0) {       // den (col 65) / y (col 64) extraction
        #pragma unroll
        for (int m = 0; m < 2; ++m)
            #pragma unroll
            for (int r = 0; r < 4; ++r) {
                int t = m * 16 + hi * 4 + r;
                if (lo == 0) ytmp[t] = acc[m][4][r];
                if (lo == 1) rden_l[t] = (acc[m][4][r] > 0.f) ? 1.f / acc[m][4][r] : 0.f;
            }
    }
    __syncthreads();
    if (w == 0) {
        float* xout = out + (size_t)s * NT * NF;
        #pragma unroll
        for (int m = 0; m < 2; ++m)
            #pragma unroll
            for (int n = 0; n < 4; ++n)
                #pragma unroll
                for (int r = 0; r < 4; ++r) {
                    int t = m * 16 + hi * 4 + r, f = n * 16 + lo;
                    xout[t * NF + f] = acc[m][n][r] * rden_l[t];
                }
    }
    if (tid < 32) {
        out[OY + (size_t)s * NT + tid] = ytmp[tid] * rden_l[tid];
        rden_g[(size_t)s * NT + tid] = rden_l[tid];
    }
}

// ---------- alphas: raw-mask read (contiguous tid*4 bytes), write at floor ----------
__global__ __launch_bounds__(256) void alphas_k(const void* __restrict__ mask,
        const float* __restrict__ e, const float* __restrict__ rden_g,
        float* __restrict__ out) {
    const int tid = threadIdx.x;
    const int blk = blockIdx.x;               // 4096 blocks: (s, eighth)
    const int s = blk >> 3;
    const int tq = tid & 7;
    const f32x4 rd4 = *(const f32x4*)(rden_g + (size_t)s * NT + tq * 4);
    const float* erow = e + (size_t)s * NB;
    float* aout = out + OA + (size_t)s * NB * NT;
    const int b0 = (blk & 7) * 256 + (tid >> 3);
    const int isbyte = detect_isbyte(mask, tid);

    float ev[8];
    #pragma unroll
    for (int j = 0; j < 8; ++j) ev[j] = erow[b0 + j * 32];

    if (isbyte) {
        // byte at mask[s*65536 + b*32 + tq*4] = base + j*1024 + tid*4 (contiguous)
        const unsigned char* base = (const unsigned char*)mask
                                  + (size_t)s * 65536 + (size_t)(blk & 7) * 8192;
        uchar4 m4[8];
        #pragma unroll
        for (int j = 0; j < 8; ++j)
            m4[j] = *(const uchar4*)(base + j * 1024 + tid * 4);
        #pragma unroll
        for (int j = 0; j < 8; ++j) {
            const int b = b0 + j * 32;
            f32x4 v;
            v.x = m4[j].x ? ev[j] * rd4.x : 0.f;
            v.y = m4[j].y ? ev[j] * rd4.y : 0.f;
            v.z = m4[j].z ? ev[j] * rd4.z : 0.f;
            v.w = m4[j].w ? ev[j] * rd4.w : 0.f;
            *(f32x4*)(aout + (size_t)b * NT + tq * 4) = v;
        }
    } else {
        // int32: uint4 (4 ints) at index s*16384 + (blk&7)*2048 + j*256 + tid
        const uint4* mi = (const uint4*)mask;
        const size_t mbase = (size_t)s * 16384 + (size_t)(blk & 7) * 2048;
        uint4 m4[8];
        #pragma unroll
        for (int j = 0; j < 8; ++j)
            m4[j] = mi[mbase + j * 256 + tid];
        #pragma unroll
        for (int j = 0; j < 8; ++j) {
            const int b = b0 + j * 32;
            f32x4 v;
            v.x = m4[j].x ? ev[j] * rd4.x : 0.f;
            v.y = m4[j].y ? ev[j] * rd4.y : 0.f;
            v.z = m4[j].z ? ev[j] * rd4.z : 0.f;
            v.w = m4[j].w ? ev[j] * rd4.w : 0.f;
            *(f32x4*)(aout + (size_t)b * NT + tq * 4) = v;
        }
    }
}

extern "C" void kernel_launch(void* const* d_in, const int* in_sizes, int n_in,
                              void* d_out, int out_size, void* d_ws, size_t ws_size,
                              hipStream_t stream) {
    (void)in_sizes; (void)n_in; (void)out_size; (void)ws_size;
    const float* X   = (const float*)d_in[0];
    const float* bgX = (const float*)d_in[1];
    const float* bgy = (const float*)d_in[2];
    const void*  nh  = d_in[3];
    const float* W1  = (const float*)d_in[4];
    const float* b1v = (const float*)d_in[5];
    const float* W2  = (const float*)d_in[6];
    const float* b2v = (const float*)d_in[7];
    float* out = (float*)d_out;
    char* ws = (char*)d_ws;

    // ws layout: [pad 4096][enc 1.31MB — rden_g overlays head, safe: enc dead after
    //  dots_k][dots/e 4MB][fb 320KB]   (pmask buffer deleted)
    float* enc = (float*)(ws + 4096);
    float* rden_g = (float*)(ws + 4096);
    float* Xe = enc;
    float* Be = enc + (size_t)NS * NH;
    float* dots = (float*)(ws + 4096 + (size_t)(NS + NB) * NH * 4);
    unsigned short* bgXT2 = (unsigned short*)((char*)dots + (size_t)NS * NB * 4);

    prep2_k<<<ENC_B + TR_B, 256, 0, stream>>>(X, bgX, bgy, W1, b1v, W2, b2v, enc, bgXT2);
    dots_k<<<dim3(NB / 64, NS / 64), 256, 0, stream>>>(Xe, Be, dots);
    fusedA_k<<<NS, 256, 0, stream>>>(nh, dots, bgXT2, rden_g, out);
    alphas_k<<<NS * 8, 256, 0, stream>>>(nh, dots, rden_g, out);
}

// Round 17
// 111.749 us; speedup vs baseline: 1.1088x; 1.1088x over previous
//
#include <hip/hip_runtime.h>
#include <hip/hip_bf16.h>

#define NS 512
#define NB 2048
#define NT 32
#define NF 64
#define NH 128
#define NFX 80    // B cols: 64 bgX + y(64) + ones(65) + zeros(66..79)
#define PSTR 81   // accumulator stride (bank-conflict-free)
#define PARTS_STRIDE (NT * PSTR)   // 2592 floats per partial

// output float offsets: [leaf_xs (S,T,F)][leaf_y (S,T)][alphas (S,B,T)]
#define OY  ((size_t)NS * NT * NF)
#define OA  (OY + (size_t)NS * NT)

#define ENC_B  1280
#define TR_B   32

typedef __attribute__((ext_vector_type(8))) short bf16x8;
typedef __attribute__((ext_vector_type(4))) float f32x4;

__device__ __forceinline__ unsigned short f2bfu(float x) {
    __hip_bfloat16 h = __float2bfloat16(x);
    return __builtin_bit_cast(unsigned short, h);
}

// monotone float <-> uint mapping for atomicMax over f32 (handles negatives)
__device__ __forceinline__ unsigned int fmap(float x) {
    unsigned int b = __float_as_uint(x);
    return (b & 0x80000000u) ? ~b : (b | 0x80000000u);
}
__device__ __forceinline__ float funmap(unsigned int m) {
    unsigned int b = (m & 0x80000000u) ? (m & 0x7FFFFFFFu) : ~m;
    return __uint_as_float(b);
}

// bit j of result = (byte j of v != 0), j in [0,16)
__device__ __forceinline__ unsigned int pack16_bytes(uint4 v) {
    unsigned int r = 0;
    unsigned int xs[4] = {v.x, v.y, v.z, v.w};
    #pragma unroll
    for (int i = 0; i < 4; ++i) {
        unsigned int x = xs[i];
        unsigned int t = (x | ((x & 0x7F7F7F7Fu) + 0x7F7F7F7Fu)) & 0x80808080u;
        t >>= 7;
        unsigned int n = (t | (t >> 7) | (t >> 14) | (t >> 21)) & 0xFu;
        r |= n << (i * 4);
    }
    return r;
}

// per-wave mask layout detect over the 4KB header (uniform w.h.p.)
__device__ __forceinline__ int detect_isbyte(const void* mask, int tid) {
    uint4 v = ((const uint4*)mask)[tid & 255];
    return (__ballot(((v.x | v.y | v.z | v.w) & 0xFFFFFF00u) != 0u) != 0ull);
}

// ---------- prep2: encode (0..1279) + frag-transpose (1280..1311) + rowmax init (1312) ----------
__global__ __launch_bounds__(256) void prep2_k(
        const float* __restrict__ X, const float* __restrict__ bgX,
        const float* __restrict__ bgy,
        const float* __restrict__ W1, const float* __restrict__ b1,
        const float* __restrict__ W2, const float* __restrict__ b2,
        float* __restrict__ enc, unsigned short* __restrict__ bgXT2,
        unsigned int* __restrict__ rowmax) {
    __shared__ float cbuf[64 * 65];
    const int blk = blockIdx.x;
    const int tid = threadIdx.x;

    if (blk < ENC_B) {                   // ---- encode branch: 2 rows per block ----
        const int r0 = blk * 2;
        float* xr = cbuf;                // [2][64]
        float* hr = cbuf + 128;          // [2][128]
        if (tid < 128) {
            int r = tid >> 6, c = tid & 63;
            int row = r0 + r;
            const float* src = (row < NS) ? (X + (size_t)row * NF)
                                          : (bgX + (size_t)(row - NS) * NF);
            xr[r * 64 + c] = src[c];
        }
        __syncthreads();
        const int j = tid & 127, h = tid >> 7;
        const float* xh = xr + h * 64;
        float a1 = b1[j];
        #pragma unroll 4
        for (int f = 0; f < NF; ++f)
            a1 = fmaf(xh[f], W1[f * NH + j], a1);
        hr[h * 128 + j] = tanhf(a1);
        __syncthreads();
        const float* hh = hr + h * 128;
        float a2 = b2[j];
        #pragma unroll 4
        for (int k = 0; k < NH; ++k)
            a2 = fmaf(hh[k], W2[k * NH + j], a2);
        enc[(size_t)(r0 + h) * NH + j] = a2;
        return;
    }

    if (blk < ENC_B + TR_B) {            // ---- frag-transpose: 64 b's per block ----
        const int bb0 = blk - ENC_B;     // 0..31
        const int b0 = bb0 * 64;
        float (*t_lds)[65] = (float(*)[65])cbuf;
        #pragma unroll
        for (int it = 0; it < 4; ++it) {
            int idx = (it * 256 + tid) * 4;
            int r = idx >> 6, c = idx & 63;
            *(float4*)(&t_lds[r][c]) = *(const float4*)(bgX + (size_t)(b0 + r) * NF + c);
        }
        __syncthreads();
        uint4* fb = (uint4*)bgXT2;
        const int c2 = tid >> 7;
        const int cg = bb0 * 2 + c2;
        for (int idx = tid & 127; idx < 320; idx += 128) {
            const int n = idx >> 6, l = idx & 63;
            const int lo = l & 15, hi = l >> 4;
            union { unsigned short u[8]; uint4 q; } pk;
            if (n < 4) {
                #pragma unroll
                for (int jj = 0; jj < 8; ++jj)
                    pk.u[jj] = f2bfu(t_lds[c2 * 32 + hi * 8 + jj][n * 16 + lo]);
            } else {
                #pragma unroll
                for (int jj = 0; jj < 8; ++jj) {
                    if (lo == 0)      pk.u[jj] = f2bfu(bgy[b0 + c2 * 32 + hi * 8 + jj]);
                    else if (lo == 1) pk.u[jj] = 0x3F80;      // bf16 1.0
                    else              pk.u[jj] = 0;
                }
            }
            fb[((size_t)cg * 5 + n) * 64 + l] = pk.q;
        }
        return;
    }

    // ---- rowmax init branch (1 block): zero 512 u32 (0 < every fmap value) ----
    if (tid < 128)
        *(uint4*)(&rowmax[tid * 4]) = make_uint4(0u, 0u, 0u, 0u);
}

// ---------- dots = X_enc @ bg_enc^T; + deterministic per-row atomicMax ----------
__global__ __launch_bounds__(256) void dots_k(const float* __restrict__ Xe,
        const float* __restrict__ Be, float* __restrict__ dots,
        unsigned int* __restrict__ rowmax) {
    __shared__ float At[64 * 68];
    __shared__ float Bt[64 * 68];
    const int s0 = blockIdx.y * 64, b0 = blockIdx.x * 64;
    const int tid = threadIdx.x;
    const int ts = tid >> 4, tb = tid & 15;
    float acc[4][4] = {};
    for (int kt = 0; kt < 2; ++kt) {
        __syncthreads();
        #pragma unroll
        for (int it = 0; it < 4; ++it) {
            int idx = tid * 4 + it * 1024;
            int r = idx >> 6, k = idx & 63;
            *(float4*)(&At[r * 68 + k]) = *(const float4*)(Xe + (size_t)(s0 + r) * NH + kt * 64 + k);
            float4 bvv = *(const float4*)(Be + (size_t)(b0 + r) * NH + kt * 64 + k);
            Bt[(k + 0) * 68 + r] = bvv.x;
            Bt[(k + 1) * 68 + r] = bvv.y;
            Bt[(k + 2) * 68 + r] = bvv.z;
            Bt[(k + 3) * 68 + r] = bvv.w;
        }
        __syncthreads();
        #pragma unroll 4
        for (int k = 0; k < 64; ++k) {
            float4 bq = *(const float4*)(&Bt[k * 68 + tb * 4]);
            float a[4];
            #pragma unroll
            for (int i = 0; i < 4; ++i) a[i] = At[(ts + 16 * i) * 68 + k];
            #pragma unroll
            for (int i = 0; i < 4; ++i) {
                acc[i][0] = fmaf(a[i], bq.x, acc[i][0]);
                acc[i][1] = fmaf(a[i], bq.y, acc[i][1]);
                acc[i][2] = fmaf(a[i], bq.z, acc[i][2]);
                acc[i][3] = fmaf(a[i], bq.w, acc[i][3]);
            }
        }
    }
    #pragma unroll
    for (int i = 0; i < 4; ++i) {
        float4 v = make_float4(acc[i][0], acc[i][1], acc[i][2], acc[i][3]);
        *(float4*)(&dots[(size_t)(s0 + ts + 16 * i) * NB + b0 + tb * 4]) = v;
        // per-row max: reduce across the 16 lanes sharing ts, then atomicMax
        float rm = fmaxf(fmaxf(acc[i][0], acc[i][1]), fmaxf(acc[i][2], acc[i][3]));
        #pragma unroll
        for (int off = 1; off <= 8; off <<= 1)
            rm = fmaxf(rm, __shfl_xor(rm, off, 64));
        if (tb == 0)
            atomicMax(&rowmax[s0 + ts + 16 * i], fmap(rm));
    }
}

// ---------- fusedB: (s, half) blocks — wave-private mask pack + exp(global M) +
//            MFMA partial einsum -> parts_g[blk]. 1024 blocks, barrier-free core. ----------
__global__ __launch_bounds__(256) void fusedB_k(const void* __restrict__ mask,
        float* __restrict__ dots, const unsigned short* __restrict__ bgXT2,
        const unsigned int* __restrict__ rowmax, float* __restrict__ parts_g) {
    __shared__ __align__(16) unsigned int mrow[1024];    // 4KB (wave-private slices)
    __shared__ __align__(16) unsigned short e_bf[1024];  // 2KB (wave-private slices)
    __shared__ float part[NT * PSTR];                    // 10.4KB reduce slot

    const int blk = blockIdx.x;          // s*2 + hb
    const int s = blk >> 1, hb = blk & 1;
    const int tid = threadIdx.x;
    const int lane = tid & 63, w = tid >> 6;
    const int lo = lane & 15, hi = lane >> 4;

    // ---- phase 0: dots loads + wave-private mask pack (no barriers) ----
    float* drow = dots + (size_t)s * NB + hb * 1024;
    float4 d0 = *(const float4*)(drow + tid * 4);
    const float Ms = funmap(rowmax[s]);
    const int isbyte = detect_isbyte(mask, tid);
    if (isbyte) {                        // wave's 8KB of the half-row (8 x 1KB)
        const char* base = (const char*)mask + (size_t)s * 65536 + hb * 32768 + w * 8192;
        #pragma unroll
        for (int k = 0; k < 8; ++k) {
            uint4 q = *(const uint4*)(base + k * 1024 + lane * 16);
            unsigned int p = pack16_bytes(q);
            unsigned int p1 = (unsigned int)__shfl_down((int)p, 1, 64);
            if ((lane & 1) == 0)
                mrow[w * 256 + k * 32 + (lane >> 1)] = p | (p1 << 16);
        }
    } else {                             // int32 fallback: wave's 32KB
        const char* base = (const char*)mask + (size_t)s * 262144 + hb * 131072 + w * 32768;
        for (int k = 0; k < 32; ++k) {
            uint4 v = *(const uint4*)(base + k * 1024 + lane * 16);
            unsigned int r = (v.x ? 1u : 0u) | (v.y ? 2u : 0u) |
                             (v.z ? 4u : 0u) | (v.w ? 8u : 0u);
            r |= ((unsigned int)__shfl_down((int)r, 1, 64)) << 4;
            r |= ((unsigned int)__shfl_down((int)r, 2, 64)) << 8;
            r |= ((unsigned int)__shfl_down((int)r, 4, 64)) << 16;
            if ((lane & 7) == 0)
                mrow[w * 256 + k * 8 + (lane >> 3)] = r;
        }
    }

    // ---- phase 1: exp with global row max; e -> dots (in place) + LDS bf16 ----
    float ev[4] = {d0.x, d0.y, d0.z, d0.w};
    unsigned short eu[4];
    #pragma unroll
    for (int q = 0; q < 4; ++q) { ev[q] = __expf(ev[q] - Ms); eu[q] = f2bfu(ev[q]); }
    *(float4*)(drow + tid * 4) = make_float4(ev[0], ev[1], ev[2], ev[3]);
    uint2 epk = make_uint2((unsigned int)eu[0] | ((unsigned int)eu[1] << 16),
                           (unsigned int)eu[2] | ((unsigned int)eu[3] << 16));
    *(uint2*)(&e_bf[tid * 4]) = epk;     // tid*4 spans exactly wave w's slice
    // NO barrier: einsum reads only this wave's mrow/e_bf slices.

    // ---- phase 2: MFMA over this half's K (wave w owns local b in [w*256,+256)) ----
    f32x4 acc[2][5] = {};
    const uint4* fb = (const uint4*)bgXT2;
    #pragma unroll 2
    for (int ks = 0; ks < 8; ++ks) {
        const int bb = w * 256 + ks * 32 + hi * 8;
        uint4 ew4 = *(const uint4*)(&e_bf[bb]);
        uint4 m0 = *(const uint4*)(&mrow[bb]);
        uint4 m1 = *(const uint4*)(&mrow[bb + 4]);
        unsigned int ew[4] = {ew4.x, ew4.y, ew4.z, ew4.w};
        unsigned int mv[8] = {m0.x, m0.y, m0.z, m0.w, m1.x, m1.y, m1.z, m1.w};
        unsigned int A0[4], A1[4];
        #pragma unroll
        for (int p = 0; p < 4; ++p) {
            unsigned int mlo = mv[2 * p]     >> lo;
            unsigned int mhi = mv[2 * p + 1] >> lo;
            unsigned int k0 = ((mlo & 1u)       ? 0x0000FFFFu : 0u) |
                              ((mhi & 1u)       ? 0xFFFF0000u : 0u);
            unsigned int k1 = ((mlo & 0x10000u) ? 0x0000FFFFu : 0u) |
                              ((mhi & 0x10000u) ? 0xFFFF0000u : 0u);
            A0[p] = ew[p] & k0;
            A1[p] = ew[p] & k1;
        }
        bf16x8 a0 = __builtin_bit_cast(bf16x8, make_uint4(A0[0], A0[1], A0[2], A0[3]));
        bf16x8 a1 = __builtin_bit_cast(bf16x8, make_uint4(A1[0], A1[1], A1[2], A1[3]));
        const int cg = hb * 32 + w * 8 + ks;
        const uint4* fr = fb + ((size_t)cg * 5) * 64 + lane;
        #pragma unroll
        for (int n = 0; n < 5; ++n) {
            uint4 bv = fr[n * 64];
            bf16x8 bfr = __builtin_bit_cast(bf16x8, bv);
            acc[0][n] = __builtin_amdgcn_mfma_f32_16x16x32_bf16(a0, bfr, acc[0][n], 0, 0, 0);
            acc[1][n] = __builtin_amdgcn_mfma_f32_16x16x32_bf16(a1, bfr, acc[1][n], 0, 0, 0);
        }
    }

    // ---- phase 3: sequential intra-block reduce into w0 ----
    for (int src = 1; src < 4; ++src) {
        __syncthreads();
        if (w == src) {
            #pragma unroll
            for (int m = 0; m < 2; ++m)
                #pragma unroll
                for (int n = 0; n < 5; ++n)
                    #pragma unroll
                    for (int r = 0; r < 4; ++r) {
                        int t = m * 16 + hi * 4 + r, f = n * 16 + lo;
                        part[t * PSTR + f] = acc[m][n][r];
                    }
        }
        __syncthreads();
        if (w == 0) {
            #pragma unroll
            for (int m = 0; m < 2; ++m)
                #pragma unroll
                for (int n = 0; n < 5; ++n)
                    #pragma unroll
                    for (int r = 0; r < 4; ++r) {
                        int t = m * 16 + hi * 4 + r, f = n * 16 + lo;
                        acc[m][n][r] += part[t * PSTR + f];
                    }
        }
    }
    // w0 stores block total into part, then whole block streams it out coalesced
    if (w == 0) {
        #pragma unroll
        for (int m = 0; m < 2; ++m)
            #pragma unroll
            for (int n = 0; n < 5; ++n)
                #pragma unroll
                for (int r = 0; r < 4; ++r) {
                    int t = m * 16 + hi * 4 + r, f = n * 16 + lo;
                    part[t * PSTR + f] = acc[m][n][r];
                }
    }
    __syncthreads();
    float* pg = parts_g + (size_t)blk * PARTS_STRIDE;
    #pragma unroll
    for (int k = 0; k < 11; ++k) {
        int e = k * 256 + tid;
        if (e < PARTS_STRIDE) pg[e] = part[e];
    }
}

// ---------- reduceC: sum 2 partials per s, normalize, write leaf_xs / leaf_y / rden ----------
__global__ __launch_bounds__(256) void reduceC_k(const float* __restrict__ parts_g,
        float* __restrict__ rden_g, float* __restrict__ out) {
    __shared__ float buf[NT * PSTR];
    __shared__ float rden_l[NT];
    const int s = blockIdx.x;
    const int tid = threadIdx.x;
    const float* p0 = parts_g + (size_t)(s * 2 + 0) * PARTS_STRIDE;
    const float* p1 = parts_g + (size_t)(s * 2 + 1) * PARTS_STRIDE;
    #pragma unroll
    for (int k = 0; k < 11; ++k) {
        int e = k * 256 + tid;
        if (e < PARTS_STRIDE) buf[e] = p0[e] + p1[e];
    }
    __syncthreads();
    if (tid < NT) {
        float den = buf[tid * PSTR + 65];
        float rd = (den > 0.f) ? 1.f / den : 0.f;
        rden_l[tid] = rd;
        rden_g[(size_t)s * NT + tid] = rd;
        out[OY + (size_t)s * NT + tid] = buf[tid * PSTR + 64] * rd;
    }
    __syncthreads();
    float* xout = out + (size_t)s * NT * NF;
    #pragma unroll
    for (int k = 0; k < 8; ++k) {
        int e = k * 256 + tid;
        int t = e >> 6, f = e & 63;
        xout[e] = buf[t * PSTR + f] * rden_l[t];
    }
}

// ---------- alphas: raw-mask read (contiguous tid*4 bytes), write at floor ----------
__global__ __launch_bounds__(256) void alphas_k(const void* __restrict__ mask,
        const float* __restrict__ e, const float* __restrict__ rden_g,
        float* __restrict__ out) {
    const int tid = threadIdx.x;
    const int blk = blockIdx.x;               // 4096 blocks: (s, eighth)
    const int s = blk >> 3;
    const int tq = tid & 7;
    const f32x4 rd4 = *(const f32x4*)(rden_g + (size_t)s * NT + tq * 4);
    const float* erow = e + (size_t)s * NB;
    float* aout = out + OA + (size_t)s * NB * NT;
    const int b0 = (blk & 7) * 256 + (tid >> 3);
    const int isbyte = detect_isbyte(mask, tid);

    float ev[8];
    #pragma unroll
    for (int j = 0; j < 8; ++j) ev[j] = erow[b0 + j * 32];

    if (isbyte) {
        const unsigned char* base = (const unsigned char*)mask
                                  + (size_t)s * 65536 + (size_t)(blk & 7) * 8192;
        uchar4 m4[8];
        #pragma unroll
        for (int j = 0; j < 8; ++j)
            m4[j] = *(const uchar4*)(base + j * 1024 + tid * 4);
        #pragma unroll
        for (int j = 0; j < 8; ++j) {
            const int b = b0 + j * 32;
            f32x4 v;
            v.x = m4[j].x ? ev[j] * rd4.x : 0.f;
            v.y = m4[j].y ? ev[j] * rd4.y : 0.f;
            v.z = m4[j].z ? ev[j] * rd4.z : 0.f;
            v.w = m4[j].w ? ev[j] * rd4.w : 0.f;
            *(f32x4*)(aout + (size_t)b * NT + tq * 4) = v;
        }
    } else {
        const uint4* mi = (const uint4*)mask;
        const size_t mbase = (size_t)s * 16384 + (size_t)(blk & 7) * 2048;
        uint4 m4[8];
        #pragma unroll
        for (int j = 0; j < 8; ++j)
            m4[j] = mi[mbase + j * 256 + tid];
        #pragma unroll
        for (int j = 0; j < 8; ++j) {
            const int b = b0 + j * 32;
            f32x4 v;
            v.x = m4[j].x ? ev[j] * rd4.x : 0.f;
            v.y = m4[j].y ? ev[j] * rd4.y : 0.f;
            v.z = m4[j].z ? ev[j] * rd4.z : 0.f;
            v.w = m4[j].w ? ev[j] * rd4.w : 0.f;
            *(f32x4*)(aout + (size_t)b * NT + tq * 4) = v;
        }
    }
}

extern "C" void kernel_launch(void* const* d_in, const int* in_sizes, int n_in,
                              void* d_out, int out_size, void* d_ws, size_t ws_size,
                              hipStream_t stream) {
    (void)in_sizes; (void)n_in; (void)out_size; (void)ws_size;
    const float* X   = (const float*)d_in[0];
    const float* bgX = (const float*)d_in[1];
    const float* bgy = (const float*)d_in[2];
    const void*  nh  = d_in[3];
    const float* W1  = (const float*)d_in[4];
    const float* b1v = (const float*)d_in[5];
    const float* W2  = (const float*)d_in[6];
    const float* b2v = (const float*)d_in[7];
    float* out = (float*)d_out;
    char* ws = (char*)d_ws;

    // ws layout: [pad 4096][enc 1.31MB — rden_g overlays head, safe: enc dead after
    //  dots_k][dots/e 4MB][fb 320KB][rowmax 2KB pad 4KB][parts 10.62MB]
    float* enc = (float*)(ws + 4096);
    float* rden_g = (float*)(ws + 4096);
    float* Xe = enc;
    float* Be = enc + (size_t)NS * NH;
    float* dots = (float*)(ws + 4096 + (size_t)(NS + NB) * NH * 4);
    unsigned short* bgXT2 = (unsigned short*)((char*)dots + (size_t)NS * NB * 4);
    unsigned int* rowmax = (unsigned int*)((char*)bgXT2 + (size_t)64 * 5 * 64 * 16);
    float* parts_g = (float*)((char*)rowmax + 4096);

    prep2_k<<<ENC_B + TR_B + 1, 256, 0, stream>>>(X, bgX, bgy, W1, b1v, W2, b2v,
                                                  enc, bgXT2, rowmax);
    dots_k<<<dim3(NB / 64, NS / 64), 256, 0, stream>>>(Xe, Be, dots, rowmax);
    fusedB_k<<<NS * 2, 256, 0, stream>>>(nh, dots, bgXT2, rowmax, parts_g);
    reduceC_k<<<NS, 256, 0, stream>>>(parts_g, rden_g, out);
    alphas_k<<<NS * 8, 256, 0, stream>>>(nh, dots, rden_g, out);
}

// Round 18
// 104.878 us; speedup vs baseline: 1.1814x; 1.0655x over previous
//
#include <hip/hip_runtime.h>
#include <hip/hip_bf16.h>

#define NS 512
#define NB 2048
#define NT 32
#define NF 64
#define NH 128
#define NFX 80    // B cols: 64 bgX + y(64) + ones(65) + zeros(66..79)
#define PSTR 81   // part[] stride (81 kills the 4-way bank conflict, 245K/rep in R13)

// output float offsets: [leaf_xs (S,T,F)][leaf_y (S,T)][alphas (S,B,T)]
#define OY  ((size_t)NS * NT * NF)
#define OA  (OY + (size_t)NS * NT)

// prep grid: layer1 (0..79), frag-transpose (80..111), pack (112..2159)
#define L1_B   80
#define TR_B   32
#define PACK_B 2048

typedef __attribute__((ext_vector_type(8))) short bf16x8;
typedef __attribute__((ext_vector_type(4))) float f32x4;

__device__ __forceinline__ unsigned short f2bfu(float x) {
    __hip_bfloat16 h = __float2bfloat16(x);
    return __builtin_bit_cast(unsigned short, h);
}

// bit j of result = (byte j of v != 0), j in [0,16)
__device__ __forceinline__ unsigned int pack16_bytes(uint4 v) {
    unsigned int r = 0;
    unsigned int xs[4] = {v.x, v.y, v.z, v.w};
    #pragma unroll
    for (int i = 0; i < 4; ++i) {
        unsigned int x = xs[i];
        unsigned int t = (x | ((x & 0x7F7F7F7Fu) + 0x7F7F7F7Fu)) & 0x80808080u;
        t >>= 7;
        unsigned int n = (t | (t >> 7) | (t >> 14) | (t >> 21)) & 0xFu;
        r |= n << (i * 4);
    }
    return r;
}

// ---------- prep: layer1 GEMM + frag-transpose + pack (wave-contiguous) ----------
__global__ __launch_bounds__(256) void prep_k(const void* mask,
        unsigned long long* pm,
        const float* __restrict__ X, const float* __restrict__ bgX,
        const float* __restrict__ bgy,
        const float* __restrict__ W1, const float* __restrict__ b1,
        float* __restrict__ enc1, unsigned short* __restrict__ bgXT2) {
    __shared__ float cbuf[2 * 64 * 68];               // 34.8KB, shared by branches
    const int blk = blockIdx.x;
    const int tid = threadIdx.x;

    if (blk < L1_B) {        // ---- layer1: 64x64 out tile, enc1 = tanh(X*W1 + b1) ----
        const int bx = blk & 1, by = blk >> 1;
        float (*Xt)[68] = (float(*)[68])cbuf;
        float (*Wt)[68] = (float(*)[68])(cbuf + 64 * 68);
        const int r0 = by * 64;                       // 512 % 64 == 0: no straddle
        const float* srcbase = (r0 < NS) ? (X + (size_t)r0 * NF)
                                         : (bgX + (size_t)(r0 - NS) * NF);
        #pragma unroll
        for (int it = 0; it < 4; ++it) {
            int idx = tid * 4 + it * 1024;
            int r = idx >> 6, c = idx & 63;
            *(float4*)(&Xt[r][c]) = *(const float4*)(srcbase + (size_t)r * NF + c);
            *(float4*)(&Wt[r][c]) = *(const float4*)(W1 + (size_t)r * NH + bx * 64 + c);
        }
        __syncthreads();
        const int ts = tid >> 4, tb = tid & 15;
        float4 bq = *(const float4*)(b1 + bx * 64 + tb * 4);
        float acc[4][4];
        #pragma unroll
        for (int i = 0; i < 4; ++i) {
            acc[i][0] = bq.x; acc[i][1] = bq.y; acc[i][2] = bq.z; acc[i][3] = bq.w;
        }
        #pragma unroll 4
        for (int k = 0; k < 64; ++k) {
            float4 wq = *(const float4*)(&Wt[k][tb * 4]);
            float a[4];
            #pragma unroll
            for (int i = 0; i < 4; ++i) a[i] = Xt[ts + 16 * i][k];
            #pragma unroll
            for (int i = 0; i < 4; ++i) {
                acc[i][0] = fmaf(a[i], wq.x, acc[i][0]);
                acc[i][1] = fmaf(a[i], wq.y, acc[i][1]);
                acc[i][2] = fmaf(a[i], wq.z, acc[i][2]);
                acc[i][3] = fmaf(a[i], wq.w, acc[i][3]);
            }
        }
        #pragma unroll
        for (int i = 0; i < 4; ++i) {
            float4 v = make_float4(tanhf(acc[i][0]), tanhf(acc[i][1]),
                                   tanhf(acc[i][2]), tanhf(acc[i][3]));
            *(float4*)(&enc1[(size_t)(r0 + ts + 16 * i) * NH + bx * 64 + tb * 4]) = v;
        }
        return;
    }

    if (blk < L1_B + TR_B) { // ---- frag-transpose: 64 b's -> MFMA-fragment-ordered B ----
        const int bb0 = blk - L1_B;      // 0..31
        const int b0 = bb0 * 64;
        float (*t_lds)[65] = (float(*)[65])cbuf;
        #pragma unroll
        for (int it = 0; it < 4; ++it) {
            int idx = (it * 256 + tid) * 4;
            int r = idx >> 6, c = idx & 63;
            *(float4*)(&t_lds[r][c]) = *(const float4*)(bgX + (size_t)(b0 + r) * NF + c);
        }
        __syncthreads();
        uint4* fb = (uint4*)bgXT2;
        const int c2 = tid >> 7;
        const int cg = bb0 * 2 + c2;
        for (int idx = tid & 127; idx < 320; idx += 128) {
            const int n = idx >> 6, l = idx & 63;
            const int lo = l & 15, hi = l >> 4;
            union { unsigned short u[8]; uint4 q; } pk;
            if (n < 4) {
                #pragma unroll
                for (int jj = 0; jj < 8; ++jj)
                    pk.u[jj] = f2bfu(t_lds[c2 * 32 + hi * 8 + jj][n * 16 + lo]);
            } else {
                #pragma unroll
                for (int jj = 0; jj < 8; ++jj) {
                    if (lo == 0)      pk.u[jj] = f2bfu(bgy[b0 + c2 * 32 + hi * 8 + jj]);
                    else if (lo == 1) pk.u[jj] = 0x3F80;      // bf16 1.0
                    else              pk.u[jj] = 0;
                }
            }
            fb[((size_t)cg * 5 + n) * 64 + l] = pk.q;
        }
        return;
    }

    {   // ---- pack branch (R12-exact): 1 thread = 1 u64 word ----
        const int pb = blk - L1_B - TR_B;
        int* flagp = (int*)cbuf;
        if (tid == 0) *flagp = 0;
        __syncthreads();
        {
            uint4 v = ((const uint4*)mask)[tid];      // 4KB header
            if (((v.x | v.y | v.z | v.w) & 0xFFFFFF00u) != 0u) *flagp = 1;
        }
        __syncthreads();
        const int isbyte = *flagp;

        const int wv = tid >> 6, lane = tid & 63;
        unsigned long long* pmw = pm + (size_t)pb * 256 + wv * 64;
        if (isbyte) {                    // 1-byte bool: wave covers 4KB contiguous
            const char* base = (const char*)mask + (size_t)pb * 16384 + wv * 4096;
            #pragma unroll
            for (int k = 0; k < 4; ++k) {
                uint4 q = *(const uint4*)(base + k * 1024 + lane * 16);
                unsigned int p = pack16_bytes(q);
                unsigned int p1 = (unsigned int)__shfl_down((int)p, 1, 64);
                unsigned int r32 = p | (p1 << 16);
                unsigned int h32 = (unsigned int)__shfl_down((int)r32, 2, 64);
                if ((lane & 3) == 0)
                    pmw[k * 16 + (lane >> 2)] =
                        (unsigned long long)r32 | ((unsigned long long)h32 << 32);
            }
        } else {                         // int32: wave covers 16KB contiguous
            const char* base = (const char*)mask + (size_t)pb * 65536 + wv * 16384;
            #pragma unroll 4
            for (int k = 0; k < 16; ++k) {
                uint4 v = *(const uint4*)(base + k * 1024 + lane * 16);
                unsigned int r = (v.x ? 1u : 0u) | (v.y ? 2u : 0u) |
                                 (v.z ? 4u : 0u) | (v.w ? 8u : 0u);
                r |= ((unsigned int)__shfl_down((int)r, 1, 64)) << 4;
                r |= ((unsigned int)__shfl_down((int)r, 2, 64)) << 8;
                r |= ((unsigned int)__shfl_down((int)r, 4, 64)) << 16;
                unsigned long long r64 = (unsigned long long)r |
                    ((unsigned long long)(unsigned int)__shfl_down((int)r, 8, 64) << 32);
                if ((lane & 15) == 0)
                    pmw[k * 4 + (lane >> 4)] = r64;
            }
        }
    }
}

// ---------- layer2: enc = enc1 * W2 + b2 (tiled, K=128 in two staged halves) ----------
__global__ __launch_bounds__(256) void layer2_k(const float* __restrict__ enc1,
        const float* __restrict__ W2, const float* __restrict__ b2,
        float* __restrict__ enc) {
    __shared__ float Ht[64 * 68];
    __shared__ float Wt[64 * 68];
    const int bx = blockIdx.x & 1, by = blockIdx.x >> 1;
    const int tid = threadIdx.x;
    const int ts = tid >> 4, tb = tid & 15;
    const int r0 = by * 64;
    float4 bq = *(const float4*)(b2 + bx * 64 + tb * 4);
    float acc[4][4];
    #pragma unroll
    for (int i = 0; i < 4; ++i) {
        acc[i][0] = bq.x; acc[i][1] = bq.y; acc[i][2] = bq.z; acc[i][3] = bq.w;
    }
    for (int kt = 0; kt < 2; ++kt) {
        __syncthreads();
        #pragma unroll
        for (int it = 0; it < 4; ++it) {
            int idx = tid * 4 + it * 1024;
            int r = idx >> 6, c = idx & 63;
            *(float4*)(&Ht[r * 68 + c]) = *(const float4*)(enc1 + (size_t)(r0 + r) * NH + kt * 64 + c);
            *(float4*)(&Wt[r * 68 + c]) = *(const float4*)(W2 + (size_t)(kt * 64 + r) * NH + bx * 64 + c);
        }
        __syncthreads();
        #pragma unroll 4
        for (int k = 0; k < 64; ++k) {
            float4 wq = *(const float4*)(&Wt[k * 68 + tb * 4]);
            float a[4];
            #pragma unroll
            for (int i = 0; i < 4; ++i) a[i] = Ht[(ts + 16 * i) * 68 + k];
            #pragma unroll
            for (int i = 0; i < 4; ++i) {
                acc[i][0] = fmaf(a[i], wq.x, acc[i][0]);
                acc[i][1] = fmaf(a[i], wq.y, acc[i][1]);
                acc[i][2] = fmaf(a[i], wq.z, acc[i][2]);
                acc[i][3] = fmaf(a[i], wq.w, acc[i][3]);
            }
        }
    }
    #pragma unroll
    for (int i = 0; i < 4; ++i) {
        float4 v = make_float4(acc[i][0], acc[i][1], acc[i][2], acc[i][3]);
        *(float4*)(&enc[(size_t)(r0 + ts + 16 * i) * NH + bx * 64 + tb * 4]) = v;
    }
}

// ---------- dots = X_enc @ bg_enc^T; contiguous stores, k-major Bt (R12-exact) ----------
__global__ __launch_bounds__(256) void dots_k(const float* __restrict__ Xe,
        const float* __restrict__ Be, float* __restrict__ dots) {
    __shared__ float At[64 * 68];
    __shared__ float Bt[64 * 68];
    const int s0 = blockIdx.y * 64, b0 = blockIdx.x * 64;
    const int tid = threadIdx.x;
    const int ts = tid >> 4, tb = tid & 15;
    float acc[4][4] = {};
    for (int kt = 0; kt < 2; ++kt) {
        __syncthreads();
        #pragma unroll
        for (int it = 0; it < 4; ++it) {
            int idx = tid * 4 + it * 1024;
            int r = idx >> 6, k = idx & 63;
            *(float4*)(&At[r * 68 + k]) = *(const float4*)(Xe + (size_t)(s0 + r) * NH + kt * 64 + k);
            float4 bvv = *(const float4*)(Be + (size_t)(b0 + r) * NH + kt * 64 + k);
            Bt[(k + 0) * 68 + r] = bvv.x;
            Bt[(k + 1) * 68 + r] = bvv.y;
            Bt[(k + 2) * 68 + r] = bvv.z;
            Bt[(k + 3) * 68 + r] = bvv.w;
        }
        __syncthreads();
        #pragma unroll 4
        for (int k = 0; k < 64; ++k) {
            float4 bq = *(const float4*)(&Bt[k * 68 + tb * 4]);
            float a[4];
            #pragma unroll
            for (int i = 0; i < 4; ++i) a[i] = At[(ts + 16 * i) * 68 + k];
            #pragma unroll
            for (int i = 0; i < 4; ++i) {
                acc[i][0] = fmaf(a[i], bq.x, acc[i][0]);
                acc[i][1] = fmaf(a[i], bq.y, acc[i][1]);
                acc[i][2] = fmaf(a[i], bq.z, acc[i][2]);
                acc[i][3] = fmaf(a[i], bq.w, acc[i][3]);
            }
        }
    }
    #pragma unroll
    for (int i = 0; i < 4; ++i) {
        float4 v = make_float4(acc[i][0], acc[i][1], acc[i][2], acc[i][3]);
        *(float4*)(&dots[(size_t)(s0 + ts + 16 * i) * NB + b0 + tb * 4]) = v;
    }
}

// ---------- fusedA (R12-exact + PSTR=81): softmax + MFMA einsum, one block per s ----------
__global__ __launch_bounds__(256) void fusedA_k(float* __restrict__ dots,
        const unsigned long long* __restrict__ pmask,
        const unsigned short* __restrict__ bgXT2,
        float* __restrict__ rden_g, float* __restrict__ out) {
    __shared__ __align__(16) unsigned int mrow[NB];      // 8KB
    __shared__ __align__(16) unsigned short e_bf[NB];    // 4KB
    __shared__ float part[3 * NT * PSTR];                // 31KB
    __shared__ float wmax[4];
    __shared__ float rden_l[NT];
    __shared__ float ytmp[NT];

    const int s = blockIdx.x;
    const int tid = threadIdx.x;
    const int lane = tid & 63, w = tid >> 6;
    const int lo = lane & 15, hi = lane >> 4;

    float* drow = dots + (size_t)s * NB;
    float4 d0 = *(const float4*)(drow + tid * 8);
    float4 d1 = *(const float4*)(drow + tid * 8 + 4);
    const uint4* pmrow = (const uint4*)((const unsigned int*)pmask + (size_t)s * NB);
    *(uint4*)(&mrow[tid * 4]) = pmrow[tid];
    *(uint4*)(&mrow[(tid + 256) * 4]) = pmrow[tid + 256];
    float pmax = fmaxf(fmaxf(fmaxf(d0.x, d0.y), fmaxf(d0.z, d0.w)),
                       fmaxf(fmaxf(d1.x, d1.y), fmaxf(d1.z, d1.w)));
    #pragma unroll
    for (int off = 32; off >= 1; off >>= 1)
        pmax = fmaxf(pmax, __shfl_xor(pmax, off, 64));
    if (lane == 0) wmax[w] = pmax;
    __syncthreads();
    const float Ms = fmaxf(fmaxf(wmax[0], wmax[1]), fmaxf(wmax[2], wmax[3]));
    float ev[8] = {d0.x, d0.y, d0.z, d0.w, d1.x, d1.y, d1.z, d1.w};
    union { unsigned short u[8]; uint4 q; } epk;
    #pragma unroll
    for (int q = 0; q < 8; ++q) { ev[q] = __expf(ev[q] - Ms); epk.u[q] = f2bfu(ev[q]); }
    *(float4*)(drow + tid * 8)     = make_float4(ev[0], ev[1], ev[2], ev[3]);
    *(float4*)(drow + tid * 8 + 4) = make_float4(ev[4], ev[5], ev[6], ev[7]);
    *(uint4*)(&e_bf[tid * 8]) = epk.q;
    __syncthreads();

    f32x4 acc[2][5] = {};
    const uint4* fb = (const uint4*)bgXT2;
    #pragma unroll 2
    for (int ks = 0; ks < 16; ++ks) {
        const int bb = w * 512 + ks * 32 + hi * 8;
        uint4 ew4 = *(const uint4*)(&e_bf[bb]);
        uint4 m0 = *(const uint4*)(&mrow[bb]);
        uint4 m1 = *(const uint4*)(&mrow[bb + 4]);
        unsigned int ew[4] = {ew4.x, ew4.y, ew4.z, ew4.w};
        unsigned int mv[8] = {m0.x, m0.y, m0.z, m0.w, m1.x, m1.y, m1.z, m1.w};
        unsigned int A0[4], A1[4];
        #pragma unroll
        for (int p = 0; p < 4; ++p) {
            unsigned int mlo = mv[2 * p]     >> lo;
            unsigned int mhi = mv[2 * p + 1] >> lo;
            unsigned int k0 = ((mlo & 1u)       ? 0x0000FFFFu : 0u) |
                              ((mhi & 1u)       ? 0xFFFF0000u : 0u);
            unsigned int k1 = ((mlo & 0x10000u) ? 0x0000FFFFu : 0u) |
                              ((mhi & 0x10000u) ? 0xFFFF0000u : 0u);
            A0[p] = ew[p] & k0;
            A1[p] = ew[p] & k1;
        }
        bf16x8 a0 = __builtin_bit_cast(bf16x8, make_uint4(A0[0], A0[1], A0[2], A0[3]));
        bf16x8 a1 = __builtin_bit_cast(bf16x8, make_uint4(A1[0], A1[1], A1[2], A1[3]));
        const uint4* fr = fb + ((size_t)(w * 16 + ks) * 5) * 64 + lane;
        #pragma unroll
        for (int n = 0; n < 5; ++n) {
            uint4 bv = fr[n * 64];
            bf16x8 bfr = __builtin_bit_cast(bf16x8, bv);
            acc[0][n] = __builtin_amdgcn_mfma_f32_16x16x32_bf16(a0, bfr, acc[0][n], 0, 0, 0);
            acc[1][n] = __builtin_amdgcn_mfma_f32_16x16x32_bf16(a1, bfr, acc[1][n], 0, 0, 0);
        }
    }

    if (w > 0) {
        #pragma unroll
        for (int m = 0; m < 2; ++m)
            #pragma unroll
            for (int n = 0; n < 5; ++n)
                #pragma unroll
                for (int r = 0; r < 4; ++r) {
                    int t = m * 16 + hi * 4 + r, f = n * 16 + lo;
                    part[(w - 1) * (NT * PSTR) + t * PSTR + f] = acc[m][n][r];
                }
    }
    __syncthreads();
    if (w == 0) {
        #pragma unroll
        for (int m = 0; m < 2; ++m)
            #pragma unroll
            for (int r = 0; r < 4; ++r) {
                int t = m * 16 + hi * 4 + r;
                int o = t * PSTR + 64 + lo;
                float tot = acc[m][4][r] + part[o] + part[NT * PSTR + o] + part[2 * NT * PSTR + o];
                if (lo == 0) ytmp[t] = tot;
                if (lo == 1) rden_l[t] = (tot > 0.f) ? 1.f / tot : 0.f;
            }
    }
    __syncthreads();
    if (w == 0) {
        float* xout = out + (size_t)s * NT * NF;
        #pragma unroll
        for (int m = 0; m < 2; ++m)
            #pragma unroll
            for (int n = 0; n < 4; ++n)
                #pragma unroll
                for (int r = 0; r < 4; ++r) {
                    int t = m * 16 + hi * 4 + r, f = n * 16 + lo;
                    int o = t * PSTR + f;
                    float tot = acc[m][n][r] + part[o] + part[NT * PSTR + o] + part[2 * NT * PSTR + o];
                    xout[t * NF + f] = tot * rden_l[t];
                }
    }
    if (tid < 32) {
        out[OY + (size_t)s * NT + tid] = ytmp[tid] * rden_l[tid];
        rden_g[(size_t)s * NT + tid] = rden_l[tid];
    }
}

// ---------- alphas (R12-exact): 4096 blocks, preloaded reads, plain stores ----------
__global__ __launch_bounds__(256) void alphas_k(const float* __restrict__ e,
        const unsigned int* __restrict__ pmask32, const float* __restrict__ rden_g,
        float* __restrict__ out) {
    const int tid = threadIdx.x;
    const int blk = blockIdx.x;               // 4096 blocks: (s, eighth)
    const int s = blk >> 3;
    const int tq = tid & 7;
    const f32x4 rd4 = *(const f32x4*)(rden_g + (size_t)s * NT + tq * 4);
    const float* erow = e + (size_t)s * NB;
    const unsigned int* mr = pmask32 + (size_t)s * NB;
    float* aout = out + OA + (size_t)s * NB * NT;
    const int b0 = (blk & 7) * 256 + (tid >> 3);

    float ev[8];
    unsigned int mv[8];
    #pragma unroll
    for (int j = 0; j < 8; ++j) {
        ev[j] = erow[b0 + j * 32];
        mv[j] = mr[b0 + j * 32] >> (tq * 4);
    }
    #pragma unroll
    for (int j = 0; j < 8; ++j) {
        const int b = b0 + j * 32;
        f32x4 v;
        v.x = (mv[j] & 1u) ? ev[j] * rd4.x : 0.f;
        v.y = (mv[j] & 2u) ? ev[j] * rd4.y : 0.f;
        v.z = (mv[j] & 4u) ? ev[j] * rd4.z : 0.f;
        v.w = (mv[j] & 8u) ? ev[j] * rd4.w : 0.f;
        *(f32x4*)(aout + (size_t)b * NT + tq * 4) = v;
    }
}

extern "C" void kernel_launch(void* const* d_in, const int* in_sizes, int n_in,
                              void* d_out, int out_size, void* d_ws, size_t ws_size,
                              hipStream_t stream) {
    (void)in_sizes; (void)n_in; (void)out_size; (void)ws_size;
    const float* X   = (const float*)d_in[0];
    const float* bgX = (const float*)d_in[1];
    const float* bgy = (const float*)d_in[2];
    const void*  nh  = d_in[3];
    const float* W1  = (const float*)d_in[4];
    const float* b1v = (const float*)d_in[5];
    const float* W2  = (const float*)d_in[6];
    const float* b2v = (const float*)d_in[7];
    float* out = (float*)d_out;
    char* ws = (char*)d_ws;

    // ws layout: [pad 4096][enc 1.31MB — rden_g overlays head, safe: enc dead after
    //  dots_k][dots/e 4MB][pmask 4MB][fb 320KB][enc1 1.31MB]
    float* enc = (float*)(ws + 4096);
    float* rden_g = (float*)(ws + 4096);
    float* Xe = enc;
    float* Be = enc + (size_t)NS * NH;
    float* dots = (float*)(ws + 4096 + (size_t)(NS + NB) * NH * 4);
    unsigned long long* pmask = (unsigned long long*)((char*)dots + (size_t)NS * NB * 4);
    unsigned short* bgXT2 = (unsigned short*)((char*)pmask + (size_t)NS * NB * NT / 64 * 8);
    float* enc1 = (float*)((char*)bgXT2 + (size_t)64 * 5 * 64 * 16);

    prep_k<<<L1_B + TR_B + PACK_B, 256, 0, stream>>>(nh, pmask, X, bgX, bgy,
                                                     W1, b1v, enc1, bgXT2);
    layer2_k<<<L1_B, 256, 0, stream>>>(enc1, W2, b2v, enc);
    dots_k<<<dim3(NB / 64, NS / 64), 256, 0, stream>>>(Xe, Be, dots);
    fusedA_k<<<NS, 256, 0, stream>>>(dots, pmask, bgXT2, rden_g, out);
    alphas_k<<<NS * 8, 256, 0, stream>>>(dots, (const unsigned int*)pmask, rden_g, out);
}

// Round 19
// 100.339 us; speedup vs baseline: 1.2348x; 1.0452x over previous
//
#include <hip/hip_runtime.h>
#include <hip/hip_bf16.h>

#define NS 512
#define NB 2048
#define NT 32
#define NF 64
#define NH 128
#define NFX 80    // B cols: 64 bgX + y(64) + ones(65) + zeros(66..79)
#define PSTR 81   // part[] stride (81 kills the 4-way bank conflict, 245K/rep in R13)

// output float offsets: [leaf_xs (S,T,F)][leaf_y (S,T)][alphas (S,B,T)]
#define OY  ((size_t)NS * NT * NF)
#define OA  (OY + (size_t)NS * NT)

// prep grid order: enc (0..1279) FIRST (latency-bound, hides under pack),
// then tr (1280..1311), then pack (1312..3359, BW-bound backfill)
#define ENC_B  1280
#define TR_B   32
#define PACK_B 2048

typedef __attribute__((ext_vector_type(8))) short bf16x8;
typedef __attribute__((ext_vector_type(4))) float f32x4;

__device__ __forceinline__ unsigned short f2bfu(float x) {
    __hip_bfloat16 h = __float2bfloat16(x);
    return __builtin_bit_cast(unsigned short, h);
}

// bit j of result = (byte j of v != 0), j in [0,16)
__device__ __forceinline__ unsigned int pack16_bytes(uint4 v) {
    unsigned int r = 0;
    unsigned int xs[4] = {v.x, v.y, v.z, v.w};
    #pragma unroll
    for (int i = 0; i < 4; ++i) {
        unsigned int x = xs[i];
        unsigned int t = (x | ((x & 0x7F7F7F7Fu) + 0x7F7F7F7Fu)) & 0x80808080u;
        t >>= 7;
        unsigned int n = (t | (t >> 7) | (t >> 14) | (t >> 21)) & 0xFu;
        r |= n << (i * 4);
    }
    return r;
}

// ---------- prep: enc FIRST, then frag-transpose, then pack (wave-contiguous) ----------
// cbuf kept at 17.4KB (R12 size) -> 8+ blocks/CU so the pack phase keeps full occupancy.
__global__ __launch_bounds__(256) void prep_k(const void* mask,
        unsigned long long* pm,
        const float* __restrict__ X, const float* __restrict__ bgX,
        const float* __restrict__ bgy,
        const float* __restrict__ W1, const float* __restrict__ b1,
        const float* __restrict__ W2, const float* __restrict__ b2,
        float* __restrict__ enc, unsigned short* __restrict__ bgXT2) {
    __shared__ float cbuf[64 * 68];
    const int blk = blockIdx.x;
    const int tid = threadIdx.x;

    if (blk < ENC_B) {                   // ---- encode branch: 2 rows per block ----
        const int r0 = blk * 2;
        float* xr = cbuf;                // [2][64]
        float* hr = cbuf + 128;          // [2][128]
        if (tid < 128) {
            int r = tid >> 6, c = tid & 63;
            int row = r0 + r;
            const float* src = (row < NS) ? (X + (size_t)row * NF)
                                          : (bgX + (size_t)(row - NS) * NF);
            xr[r * 64 + c] = src[c];
        }
        __syncthreads();
        const int j = tid & 127, h = tid >> 7;
        const float* xh = xr + h * 64;
        float a1 = b1[j];
        #pragma unroll 4
        for (int f = 0; f < NF; ++f)
            a1 = fmaf(xh[f], W1[f * NH + j], a1);
        hr[h * 128 + j] = tanhf(a1);
        __syncthreads();
        const float* hh = hr + h * 128;
        float a2 = b2[j];
        #pragma unroll 4
        for (int k = 0; k < NH; ++k)
            a2 = fmaf(hh[k], W2[k * NH + j], a2);
        enc[(size_t)(r0 + h) * NH + j] = a2;
        return;
    }

    if (blk < ENC_B + TR_B) { // ---- frag-transpose: 64 b's -> MFMA-fragment-ordered B ----
        const int bb0 = blk - ENC_B;     // 0..31
        const int b0 = bb0 * 64;
        float (*t_lds)[65] = (float(*)[65])cbuf;
        #pragma unroll
        for (int it = 0; it < 4; ++it) {
            int idx = (it * 256 + tid) * 4;
            int r = idx >> 6, c = idx & 63;
            *(float4*)(&t_lds[r][c]) = *(const float4*)(bgX + (size_t)(b0 + r) * NF + c);
        }
        __syncthreads();
        uint4* fb = (uint4*)bgXT2;
        const int c2 = tid >> 7;
        const int cg = bb0 * 2 + c2;
        for (int idx = tid & 127; idx < 320; idx += 128) {
            const int n = idx >> 6, l = idx & 63;
            const int lo = l & 15, hi = l >> 4;
            union { unsigned short u[8]; uint4 q; } pk;
            if (n < 4) {
                #pragma unroll
                for (int jj = 0; jj < 8; ++jj)
                    pk.u[jj] = f2bfu(t_lds[c2 * 32 + hi * 8 + jj][n * 16 + lo]);
            } else {
                #pragma unroll
                for (int jj = 0; jj < 8; ++jj) {
                    if (lo == 0)      pk.u[jj] = f2bfu(bgy[b0 + c2 * 32 + hi * 8 + jj]);
                    else if (lo == 1) pk.u[jj] = 0x3F80;      // bf16 1.0
                    else              pk.u[jj] = 0;
                }
            }
            fb[((size_t)cg * 5 + n) * 64 + l] = pk.q;
        }
        return;
    }

    {   // ---- pack branch (R12-exact): 1 thread = 1 u64 word ----
        const int pb = blk - ENC_B - TR_B;
        int* flagp = (int*)cbuf;
        if (tid == 0) *flagp = 0;
        __syncthreads();
        {
            uint4 v = ((const uint4*)mask)[tid];      // 4KB header (uniform result)
            if (((v.x | v.y | v.z | v.w) & 0xFFFFFF00u) != 0u) *flagp = 1;
        }
        __syncthreads();
        const int isbyte = *flagp;

        const int wv = tid >> 6, lane = tid & 63;
        unsigned long long* pmw = pm + (size_t)pb * 256 + wv * 64;
        if (isbyte) {                    // 1-byte bool: wave covers 4KB contiguous
            const char* base = (const char*)mask + (size_t)pb * 16384 + wv * 4096;
            #pragma unroll
            for (int k = 0; k < 4; ++k) {
                uint4 q = *(const uint4*)(base + k * 1024 + lane * 16);
                unsigned int p = pack16_bytes(q);
                unsigned int p1 = (unsigned int)__shfl_down((int)p, 1, 64);
                unsigned int r32 = p | (p1 << 16);
                unsigned int h32 = (unsigned int)__shfl_down((int)r32, 2, 64);
                if ((lane & 3) == 0)
                    pmw[k * 16 + (lane >> 2)] =
                        (unsigned long long)r32 | ((unsigned long long)h32 << 32);
            }
        } else {                         // int32: wave covers 16KB contiguous
            const char* base = (const char*)mask + (size_t)pb * 65536 + wv * 16384;
            #pragma unroll 4
            for (int k = 0; k < 16; ++k) {
                uint4 v = *(const uint4*)(base + k * 1024 + lane * 16);
                unsigned int r = (v.x ? 1u : 0u) | (v.y ? 2u : 0u) |
                                 (v.z ? 4u : 0u) | (v.w ? 8u : 0u);
                r |= ((unsigned int)__shfl_down((int)r, 1, 64)) << 4;
                r |= ((unsigned int)__shfl_down((int)r, 2, 64)) << 8;
                r |= ((unsigned int)__shfl_down((int)r, 4, 64)) << 16;
                unsigned long long r64 = (unsigned long long)r |
                    ((unsigned long long)(unsigned int)__shfl_down((int)r, 8, 64) << 32);
                if ((lane & 15) == 0)
                    pmw[k * 4 + (lane >> 4)] = r64;
            }
        }
    }
}

// ---------- dots = X_enc @ bg_enc^T; contiguous stores, k-major Bt (R12-exact) ----------
__global__ __launch_bounds__(256) void dots_k(const float* __restrict__ Xe,
        const float* __restrict__ Be, float* __restrict__ dots) {
    __shared__ float At[64 * 68];
    __shared__ float Bt[64 * 68];
    const int s0 = blockIdx.y * 64, b0 = blockIdx.x * 64;
    const int tid = threadIdx.x;
    const int ts = tid >> 4, tb = tid & 15;
    float acc[4][4] = {};
    for (int kt = 0; kt < 2; ++kt) {
        __syncthreads();
        #pragma unroll
        for (int it = 0; it < 4; ++it) {
            int idx = tid * 4 + it * 1024;
            int r = idx >> 6, k = idx & 63;
            *(float4*)(&At[r * 68 + k]) = *(const float4*)(Xe + (size_t)(s0 + r) * NH + kt * 64 + k);
            float4 bvv = *(const float4*)(Be + (size_t)(b0 + r) * NH + kt * 64 + k);
            Bt[(k + 0) * 68 + r] = bvv.x;
            Bt[(k + 1) * 68 + r] = bvv.y;
            Bt[(k + 2) * 68 + r] = bvv.z;
            Bt[(k + 3) * 68 + r] = bvv.w;
        }
        __syncthreads();
        #pragma unroll 4
        for (int k = 0; k < 64; ++k) {
            float4 bq = *(const float4*)(&Bt[k * 68 + tb * 4]);
            float a[4];
            #pragma unroll
            for (int i = 0; i < 4; ++i) a[i] = At[(ts + 16 * i) * 68 + k];
            #pragma unroll
            for (int i = 0; i < 4; ++i) {
                acc[i][0] = fmaf(a[i], bq.x, acc[i][0]);
                acc[i][1] = fmaf(a[i], bq.y, acc[i][1]);
                acc[i][2] = fmaf(a[i], bq.z, acc[i][2]);
                acc[i][3] = fmaf(a[i], bq.w, acc[i][3]);
            }
        }
    }
    #pragma unroll
    for (int i = 0; i < 4; ++i) {
        float4 v = make_float4(acc[i][0], acc[i][1], acc[i][2], acc[i][3]);
        *(float4*)(&dots[(size_t)(s0 + ts + 16 * i) * NB + b0 + tb * 4]) = v;
    }
}

// ---------- fusedA (R12-exact + PSTR=81): softmax + MFMA einsum, one block per s ----------
__global__ __launch_bounds__(256) void fusedA_k(float* __restrict__ dots,
        const unsigned long long* __restrict__ pmask,
        const unsigned short* __restrict__ bgXT2,
        float* __restrict__ rden_g, float* __restrict__ out) {
    __shared__ __align__(16) unsigned int mrow[NB];      // 8KB
    __shared__ __align__(16) unsigned short e_bf[NB];    // 4KB
    __shared__ float part[3 * NT * PSTR];                // 31.1KB
    __shared__ float wmax[4];
    __shared__ float rden_l[NT];
    __shared__ float ytmp[NT];

    const int s = blockIdx.x;
    const int tid = threadIdx.x;
    const int lane = tid & 63, w = tid >> 6;
    const int lo = lane & 15, hi = lane >> 4;

    float* drow = dots + (size_t)s * NB;
    float4 d0 = *(const float4*)(drow + tid * 8);
    float4 d1 = *(const float4*)(drow + tid * 8 + 4);
    const uint4* pmrow = (const uint4*)((const unsigned int*)pmask + (size_t)s * NB);
    *(uint4*)(&mrow[tid * 4]) = pmrow[tid];
    *(uint4*)(&mrow[(tid + 256) * 4]) = pmrow[tid + 256];
    float pmax = fmaxf(fmaxf(fmaxf(d0.x, d0.y), fmaxf(d0.z, d0.w)),
                       fmaxf(fmaxf(d1.x, d1.y), fmaxf(d1.z, d1.w)));
    #pragma unroll
    for (int off = 32; off >= 1; off >>= 1)
        pmax = fmaxf(pmax, __shfl_xor(pmax, off, 64));
    if (lane == 0) wmax[w] = pmax;
    __syncthreads();
    const float Ms = fmaxf(fmaxf(wmax[0], wmax[1]), fmaxf(wmax[2], wmax[3]));
    float ev[8] = {d0.x, d0.y, d0.z, d0.w, d1.x, d1.y, d1.z, d1.w};
    union { unsigned short u[8]; uint4 q; } epk;
    #pragma unroll
    for (int q = 0; q < 8; ++q) { ev[q] = __expf(ev[q] - Ms); epk.u[q] = f2bfu(ev[q]); }
    *(float4*)(drow + tid * 8)     = make_float4(ev[0], ev[1], ev[2], ev[3]);
    *(float4*)(drow + tid * 8 + 4) = make_float4(ev[4], ev[5], ev[6], ev[7]);
    *(uint4*)(&e_bf[tid * 8]) = epk.q;
    __syncthreads();

    f32x4 acc[2][5] = {};
    const uint4* fb = (const uint4*)bgXT2;
    #pragma unroll 2
    for (int ks = 0; ks < 16; ++ks) {
        const int bb = w * 512 + ks * 32 + hi * 8;
        uint4 ew4 = *(const uint4*)(&e_bf[bb]);
        uint4 m0 = *(const uint4*)(&mrow[bb]);
        uint4 m1 = *(const uint4*)(&mrow[bb + 4]);
        unsigned int ew[4] = {ew4.x, ew4.y, ew4.z, ew4.w};
        unsigned int mv[8] = {m0.x, m0.y, m0.z, m0.w, m1.x, m1.y, m1.z, m1.w};
        unsigned int A0[4], A1[4];
        #pragma unroll
        for (int p = 0; p < 4; ++p) {
            unsigned int mlo = mv[2 * p]     >> lo;
            unsigned int mhi = mv[2 * p + 1] >> lo;
            unsigned int k0 = ((mlo & 1u)       ? 0x0000FFFFu : 0u) |
                              ((mhi & 1u)       ? 0xFFFF0000u : 0u);
            unsigned int k1 = ((mlo & 0x10000u) ? 0x0000FFFFu : 0u) |
                              ((mhi & 0x10000u) ? 0xFFFF0000u : 0u);
            A0[p] = ew[p] & k0;
            A1[p] = ew[p] & k1;
        }
        bf16x8 a0 = __builtin_bit_cast(bf16x8, make_uint4(A0[0], A0[1], A0[2], A0[3]));
        bf16x8 a1 = __builtin_bit_cast(bf16x8, make_uint4(A1[0], A1[1], A1[2], A1[3]));
        const uint4* fr = fb + ((size_t)(w * 16 + ks) * 5) * 64 + lane;
        #pragma unroll
        for (int n = 0; n < 5; ++n) {
            uint4 bv = fr[n * 64];
            bf16x8 bfr = __builtin_bit_cast(bf16x8, bv);
            acc[0][n] = __builtin_amdgcn_mfma_f32_16x16x32_bf16(a0, bfr, acc[0][n], 0, 0, 0);
            acc[1][n] = __builtin_amdgcn_mfma_f32_16x16x32_bf16(a1, bfr, acc[1][n], 0, 0, 0);
        }
    }

    if (w > 0) {
        #pragma unroll
        for (int m = 0; m < 2; ++m)
            #pragma unroll
            for (int n = 0; n < 5; ++n)
                #pragma unroll
                for (int r = 0; r < 4; ++r) {
                    int t = m * 16 + hi * 4 + r, f = n * 16 + lo;
                    part[(w - 1) * (NT * PSTR) + t * PSTR + f] = acc[m][n][r];
                }
    }
    __syncthreads();
    if (w == 0) {
        #pragma unroll
        for (int m = 0; m < 2; ++m)
            #pragma unroll
            for (int r = 0; r < 4; ++r) {
                int t = m * 16 + hi * 4 + r;
                int o = t * PSTR + 64 + lo;
                float tot = acc[m][4][r] + part[o] + part[NT * PSTR + o] + part[2 * NT * PSTR + o];
                if (lo == 0) ytmp[t] = tot;
                if (lo == 1) rden_l[t] = (tot > 0.f) ? 1.f / tot : 0.f;
            }
    }
    __syncthreads();
    if (w == 0) {
        float* xout = out + (size_t)s * NT * NF;
        #pragma unroll
        for (int m = 0; m < 2; ++m)
            #pragma unroll
            for (int n = 0; n < 4; ++n)
                #pragma unroll
                for (int r = 0; r < 4; ++r) {
                    int t = m * 16 + hi * 4 + r, f = n * 16 + lo;
                    int o = t * PSTR + f;
                    float tot = acc[m][n][r] + part[o] + part[NT * PSTR + o] + part[2 * NT * PSTR + o];
                    xout[t * NF + f] = tot * rden_l[t];
                }
    }
    if (tid < 32) {
        out[OY + (size_t)s * NT + tid] = ytmp[tid] * rden_l[tid];
        rden_g[(size_t)s * NT + tid] = rden_l[tid];
    }
}

// ---------- alphas (R12-exact): 4096 blocks, preloaded reads, plain stores ----------
__global__ __launch_bounds__(256) void alphas_k(const float* __restrict__ e,
        const unsigned int* __restrict__ pmask32, const float* __restrict__ rden_g,
        float* __restrict__ out) {
    const int tid = threadIdx.x;
    const int blk = blockIdx.x;               // 4096 blocks: (s, eighth)
    const int s = blk >> 3;
    const int tq = tid & 7;
    const f32x4 rd4 = *(const f32x4*)(rden_g + (size_t)s * NT + tq * 4);
    const float* erow = e + (size_t)s * NB;
    const unsigned int* mr = pmask32 + (size_t)s * NB;
    float* aout = out + OA + (size_t)s * NB * NT;
    const int b0 = (blk & 7) * 256 + (tid >> 3);

    float ev[8];
    unsigned int mv[8];
    #pragma unroll
    for (int j = 0; j < 8; ++j) {
        ev[j] = erow[b0 + j * 32];
        mv[j] = mr[b0 + j * 32] >> (tq * 4);
    }
    #pragma unroll
    for (int j = 0; j < 8; ++j) {
        const int b = b0 + j * 32;
        f32x4 v;
        v.x = (mv[j] & 1u) ? ev[j] * rd4.x : 0.f;
        v.y = (mv[j] & 2u) ? ev[j] * rd4.y : 0.f;
        v.z = (mv[j] & 4u) ? ev[j] * rd4.z : 0.f;
        v.w = (mv[j] & 8u) ? ev[j] * rd4.w : 0.f;
        *(f32x4*)(aout + (size_t)b * NT + tq * 4) = v;
    }
}

extern "C" void kernel_launch(void* const* d_in, const int* in_sizes, int n_in,
                              void* d_out, int out_size, void* d_ws, size_t ws_size,
                              hipStream_t stream) {
    (void)in_sizes; (void)n_in; (void)out_size; (void)ws_size;
    const float* X   = (const float*)d_in[0];
    const float* bgX = (const float*)d_in[1];
    const float* bgy = (const float*)d_in[2];
    const void*  nh  = d_in[3];
    const float* W1  = (const float*)d_in[4];
    const float* b1v = (const float*)d_in[5];
    const float* W2  = (const float*)d_in[6];
    const float* b2v = (const float*)d_in[7];
    float* out = (float*)d_out;
    char* ws = (char*)d_ws;

    // ws layout: [pad 4096][enc 1.31MB — rden_g overlays head, safe: enc dead after
    //  dots_k][dots/e 4MB][pmask 4MB][fb 320KB]
    float* enc = (float*)(ws + 4096);
    float* rden_g = (float*)(ws + 4096);
    float* Xe = enc;
    float* Be = enc + (size_t)NS * NH;
    float* dots = (float*)(ws + 4096 + (size_t)(NS + NB) * NH * 4);
    unsigned long long* pmask = (unsigned long long*)((char*)dots + (size_t)NS * NB * 4);
    unsigned short* bgXT2 = (unsigned short*)((char*)pmask + (size_t)NS * NB * NT / 64 * 8);

    prep_k<<<ENC_B + TR_B + PACK_B, 256, 0, stream>>>(nh, pmask, X, bgX, bgy,
                                                      W1, b1v, W2, b2v, enc, bgXT2);
    dots_k<<<dim3(NB / 64, NS / 64), 256, 0, stream>>>(Xe, Be, dots);
    fusedA_k<<<NS, 256, 0, stream>>>(dots, pmask, bgXT2, rden_g, out);
    alphas_k<<<NS * 8, 256, 0, stream>>>(dots, (const unsigned int*)pmask, rden_g, out);
}